// Round 1
// baseline (18679.120 us; speedup 1.0000x reference)
//
#include <hip/hip_runtime.h>
#include <math.h>

// HybridQLSTM: T=1024 steps, B=64, D_IN=256, H=256, 4 gates.
// One kernel launch per timestep; kernel boundary = device-wide barrier.
// Block (bq, g) owns gate g for batch rows {2bq, 2bq+1}, all 256 columns:
//   1) LSTM update for its rows using PREVIOUS step's gates (redundant across g,
//      with a per-gate replicated cell state -> bitwise identical, no comm needed)
//   2) stage1: hid = tanh(W1 . [x_t, h]) entirely in-block (all j)
//   3) stage2: gate = sigmoid(W2 . hid)  (hid row is fully local in LDS)

#define TS  1024
#define BB  64
#define DIN 256
#define HH  256

__global__ __launch_bounds__(512) void qlstm_step(
    const float* __restrict__ x,      // [TS, BB, DIN]
    const float* __restrict__ W1,     // [4, 512, 256]
    const float* __restrict__ b1,     // [4, 256]
    const float* __restrict__ W2,     // [4, 256, 256]
    const float* __restrict__ b2,     // [4, 256]
    float* __restrict__ gates,        // ws [4, BB, HH]  (prev step's gates in, this step's out)
    float* __restrict__ crep,         // ws [4, BB, HH]  (per-gate replicated cell state)
    float* __restrict__ out,          // d_out: stacked[TS,BB,HH] ++ hx[BB,HH] ++ cx[BB,HH]
    int t)
{
    const int j  = threadIdx.x & 255;   // output column
    const int bi = threadIdx.x >> 8;    // 0..1 (batch row within block)
    const int g  = blockIdx.y;          // gate
    const int b  = blockIdx.x * 2 + bi; // batch row
    const int bj = b * HH + j;

    __shared__ float h_s[2][HH];
    __shared__ float hid_s[2][HH];

    // ---- phase 0: LSTM update producing h_{t-1} (h=0, c=0 at t==0) ----
    float hn;
    if (t == 0) {
        hn = 0.0f;
        crep[g * BB * HH + bj] = 0.0f;            // c_{-1} = 0
    } else {
        float f = gates[0 * BB * HH + bj];
        float i = gates[1 * BB * HH + bj];
        float u = gates[2 * BB * HH + bj];
        float o = gates[3 * BB * HH + bj];
        float c = crep[g * BB * HH + bj];
        c  = f * c + i * tanhf(u);
        hn = o * tanhf(c);
        crep[g * BB * HH + bj] = c;
        if (g == 0) out[(size_t)(t - 1) * BB * HH + bj] = hn;  // stacked[t-1]
    }
    h_s[bi][j] = hn;
    __syncthreads();

    // ---- phase 1: hid[g][b][j] = tanh(b1 + sum_d comb[b][d] * W1[g][d][j]) ----
    float acc0 = b1[g * HH + j];
    float acc1 = 0.0f;
    const float* xr  = x  + ((size_t)t * BB + b) * DIN;
    const float* w1  = W1 + (size_t)g * 512 * HH + j;   // column j, coalesced across lanes
    #pragma unroll 8
    for (int d = 0; d < DIN; d += 2) {
        acc0 += xr[d]     * w1[(size_t)d       * HH];
        acc1 += xr[d + 1] * w1[(size_t)(d + 1) * HH];
    }
    const float* w1h = w1 + (size_t)DIN * HH;
    #pragma unroll 8
    for (int d = 0; d < HH; d += 2) {
        acc0 += h_s[bi][d]     * w1h[(size_t)d       * HH];
        acc1 += h_s[bi][d + 1] * w1h[(size_t)(d + 1) * HH];
    }
    hid_s[bi][j] = tanhf(acc0 + acc1);
    __syncthreads();

    // ---- phase 2: gate[g][b][k] = sigmoid(b2 + sum_j hid[b][j] * W2[g][j][k]), k==j ----
    float a0 = b2[g * HH + j];
    float a1 = 0.0f;
    const float* w2 = W2 + (size_t)g * HH * HH + j;
    #pragma unroll 8
    for (int jj = 0; jj < HH; jj += 2) {
        a0 += hid_s[bi][jj]     * w2[(size_t)jj       * HH];
        a1 += hid_s[bi][jj + 1] * w2[(size_t)(jj + 1) * HH];
    }
    gates[g * BB * HH + bj] = 1.0f / (1.0f + expf(-(a0 + a1)));
}

// After the loop: gates holds step-1023 gates, crep[0] holds c_1022.
// Produce stacked[1023], hx, cx.
__global__ __launch_bounds__(256) void qlstm_final(
    const float* __restrict__ gates,
    const float* __restrict__ crep,
    float* __restrict__ out)
{
    int idx = blockIdx.x * blockDim.x + threadIdx.x;  // [0, BB*HH)
    float f = gates[0 * BB * HH + idx];
    float i = gates[1 * BB * HH + idx];
    float u = gates[2 * BB * HH + idx];
    float o = gates[3 * BB * HH + idx];
    float c = crep[idx];  // gate-0 replica
    c = f * c + i * tanhf(u);
    float hn = o * tanhf(c);
    out[(size_t)(TS - 1) * BB * HH + idx] = hn;            // stacked[1023]
    out[(size_t)TS * BB * HH + idx]       = hn;            // hx
    out[(size_t)TS * BB * HH + BB * HH + idx] = c;         // cx
}

extern "C" void kernel_launch(void* const* d_in, const int* in_sizes, int n_in,
                              void* d_out, int out_size, void* d_ws, size_t ws_size,
                              hipStream_t stream)
{
    const float* x  = (const float*)d_in[0];  // inputs [1024,64,256]
    const float* W1 = (const float*)d_in[1];  // [4,512,256]
    const float* b1 = (const float*)d_in[2];  // [4,256]
    const float* W2 = (const float*)d_in[3];  // [4,256,256]
    const float* b2 = (const float*)d_in[4];  // [4,256]
    float* out = (float*)d_out;
    float* ws  = (float*)d_ws;

    float* gates = ws;                    // 4*64*256 floats = 256 KB
    float* crep  = ws + 4 * BB * HH;      // 4*64*256 floats = 256 KB

    dim3 grid(BB / 2, 4);   // 32 batch-pairs x 4 gates = 128 blocks
    dim3 block(512);        // 256 columns x 2 batch rows

    for (int t = 0; t < TS; ++t) {
        qlstm_step<<<grid, block, 0, stream>>>(x, W1, b1, W2, b2, gates, crep, out, t);
    }
    qlstm_final<<<BB * HH / 256, 256, 0, stream>>>(gates, crep, out);
}